// Round 6
// baseline (291.236 us; speedup 1.0000x reference)
//
#include <hip/hip_runtime.h>

typedef short short8 __attribute__((ext_vector_type(8)));
typedef int   intx8  __attribute__((ext_vector_type(8)));
typedef float floatx16 __attribute__((ext_vector_type(16)));

__device__ __forceinline__ unsigned pk4(int a, int b, int c, int d) {
    return (a & 255) | ((b & 255) << 8) | ((c & 255) << 16) | ((unsigned)(d & 255) << 24);
}

// E4M3 code + E8M0 scale exponent (esf = sf-127) -> bf16 bits. Exact, integer-only.
// NaN code (e=15,m=7) decodes to 480*2^esf like the reference (fp8 can't use the
// HW f8f6f4 path: HW would produce NaN).
__device__ __forceinline__ unsigned dec8bf(int c, int esf) {
    int s = (c & 128) << 8;
    int e = (c >> 3) & 15, m = c & 7;
    int rn = s | ((e + 120 + esf) << 7) | (m << 4);                 // normal: (1+m/8)*2^(e-7)
    int nb = (m >= 4) ? 2 : ((m >= 2) ? 1 : 0);                     // floor(log2 m)
    int rs = m ? (s | ((nb + 118 + esf) << 7) | ((m << (7 - nb)) & 0x7F)) : s;  // subnormal m*2^-9
    return (unsigned)(e ? rn : rs);
}

// ---- prepass (r4 version, unchanged: fully coalesced both sides via LDS stage).
__global__ __launch_bounds__(256) void pack_lds(
    const int* __restrict__ Pn, const int* __restrict__ Ps, const int* __restrict__ Po,
    const int* __restrict__ Sn, const int* __restrict__ Ss, const int* __restrict__ So,
    unsigned char* __restrict__ C4, unsigned char* __restrict__ C6,
    unsigned short* __restrict__ C8, unsigned char* __restrict__ St, int R)
{
    __shared__ unsigned lds[9216];                 // 36 KB, max section (fp6)
    int t = threadIdx.x, b = blockIdx.x, per = R >> 6;
    if (b < 4 * per) {                             // ---- fp4: 64 rows x 24 chunks
        int jg = b / per, rb = b - jg * per, r0 = rb << 6;
        #pragma unroll
        for (int i = 0; i < 24; ++i) {
            int idx = i * 256 + t, row = idx / 96, q4 = idx - row * 96;
            int4 v = *(const int4*)(Pn + (size_t)(r0 + row) * 1536 + jg * 384 + q4 * 4);
            lds[row * 96 + q4] = pk4(v.x, v.y, v.z, v.w);
        }
        __syncthreads();
        #pragma unroll
        for (int i = 0; i < 6; ++i) {
            int idx = i * 256 + t, j = idx >> 6, row = idx & 63;
            uint4 v = *(uint4*)&lds[row * 96 + j * 4];
            *(uint4*)(C4 + ((size_t)(jg * 24 + j) * R + r0 + row) * 16) = v;
        }
    } else if (b < 5 * per) {                      // ---- fp6
        int rb = b - 4 * per, r0 = rb << 6;
        #pragma unroll
        for (int i = 0; i < 36; ++i) {
            int idx = i * 256 + t, row = idx / 144, q4 = idx - row * 144;
            int4 v = *(const int4*)(Ps + (size_t)(r0 + row) * 576 + q4 * 4);
            lds[row * 144 + q4] = pk4(v.x, v.y, v.z, v.w);
        }
        __syncthreads();
        #pragma unroll
        for (int i = 0; i < 18; ++i) {
            int idx = i * 256 + t, seg = idx / 192, off = idx - seg * 192;
            int row = off / 3, m3 = off - row * 3;
            int w0 = row * 144 + seg * 6 + m3 * 2;
            int2 v = { (int)lds[w0], (int)lds[w0 + 1] };
            *(int2*)(C6 + ((size_t)seg * R + r0) * 24 + (size_t)off * 8) = v;
        }
    } else if (b < 6 * per) {                      // ---- fp8: decode+scale to bf16
        int rb = b - 5 * per, r0 = rb << 6;
        #pragma unroll
        for (int i = 0; i < 16; ++i) {
            int idx = i * 256 + t, row = idx >> 6, q4 = idx & 63;
            int4 c = *(const int4*)(Po + (size_t)(r0 + row) * 256 + q4 * 4);
            int e = So[(size_t)(r0 + row) * 8 + (q4 >> 3)] - 127;
            lds[row * 128 + q4 * 2]     = dec8bf(c.x & 255, e) | (dec8bf(c.y & 255, e) << 16);
            lds[row * 128 + q4 * 2 + 1] = dec8bf(c.z & 255, e) | (dec8bf(c.w & 255, e) << 16);
        }
        __syncthreads();
        #pragma unroll
        for (int i = 0; i < 8; ++i) {
            int idx = i * 256 + t, seg = idx >> 6, row = idx & 63;
            uint4 v = *(uint4*)&lds[row * 128 + seg * 4];
            *(uint4*)((unsigned char*)C8 + ((size_t)seg * R + r0 + row) * 16) = v;
        }
    } else if (b < 7 * per) {                      // ---- fp4 scale quads
        int rb = b - 6 * per, r0 = rb << 6;
        #pragma unroll
        for (int i = 0; i < 6; ++i) {
            int idx = i * 256 + t, row = idx / 24, q4 = idx - row * 24;
            int4 v = *(const int4*)(Sn + (size_t)(r0 + row) * 96 + q4 * 4);
            lds[row * 24 + q4] = pk4(v.x, v.y, v.z, v.w);
        }
        __syncthreads();
        #pragma unroll
        for (int i = 0; i < 6; ++i) {
            int idx = i * 256 + t, seg = idx >> 6, row = idx & 63;
            *(unsigned*)(St + ((size_t)seg * R + r0 + row) * 4) = lds[row * 24 + seg];
        }
    } else {                                       // ---- fp6 scale pairs
        int rb = b - 7 * per, r0 = rb << 6;
        #pragma unroll
        for (int i = 0; i < 3; ++i) {
            int idx = i * 256 + t, row = idx / 12, b2 = idx - row * 12;
            int2 v = *(const int2*)(Ss + (size_t)(r0 + row) * 24 + b2 * 2);
            lds[row * 12 + b2] = (unsigned)((v.x & 255) | ((v.y & 255) << 8));
        }
        __syncthreads();
        #pragma unroll
        for (int i = 0; i < 3; ++i) {
            int idx = i * 256 + t, seg = idx >> 6, row = idx & 63;
            *(unsigned*)(St + ((size_t)(24 + seg) * R + r0 + row) * 4) = lds[row * 12 + seg];
        }
    }
}

// ---- barrier-free direct-load MX GEMM v6: WIDE WAVE TILE.
// Block 128x256, 4 waves (2Mx2N), wave tile 64x128 = acc[2][4] of 32x32.
// 8 back-to-back MFMAs per K-step (550cy matrix-pipe work vs 275 in r1) against
// the same ~1000cy load latency -> latency-bound fraction shrinks; loads/MFMA
// 1.0 -> 0.75. Register budget at (256,2) cap 256: acc 128 + fp4 depth-3 frags
// 72 + scales/addr ~35 = ~235. (r5 ledger: LDS staging worse (barrier lockstep),
// (256,3) spills, XCD swizzle null -- the r1 barrier-free register-pipeline
// structure is kept.) Tail prefetch strays land in the adjacent ws region
// (A4->B4->A6, A8->B8->SaT; St strays stay inside rows<36); fp6 tail peeled.
__global__ __launch_bounds__(256, 2) void gemm_mx(
    const unsigned char* __restrict__ A4, const unsigned char* __restrict__ B4,
    const unsigned char* __restrict__ A6, const unsigned char* __restrict__ B6,
    const unsigned short* __restrict__ A8, const unsigned short* __restrict__ B8,
    const unsigned char* __restrict__ SaT, const unsigned char* __restrict__ SbT,
    const float* __restrict__ bias, float* __restrict__ C, int M, int N)
{
    int tid = threadIdx.x, w = tid >> 6, l = tid & 63;
    int bm = blockIdx.y, bn = blockIdx.x;
    int wm = (w >> 1) * 64, wn = (w & 1) * 128;
    int lr = l & 31, lh = l >> 5;

    floatx16 acc[2][4] = {};

    int rA[2], cB[4];
    #pragma unroll
    for (int i = 0; i < 2; ++i) rA[i] = bm * 128 + wm + i * 32 + lr;
    #pragma unroll
    for (int j = 0; j < 4; ++j) cB[j] = bn * 256 + wn + j * 32 + lr;

    // ================= fp4 (fmt 4): 48 steps of K=64, depth-3 pipeline =================
    {
        unsigned strA = 32u * (unsigned)M, strB = 32u * (unsigned)N;
        unsigned fA[2], fB[4];
        #pragma unroll
        for (int i = 0; i < 2; ++i) fA[i] = ((unsigned)lh * M + (unsigned)rA[i]) * 16u;
        #pragma unroll
        for (int j = 0; j < 4; ++j) fB[j] = ((unsigned)lh * N + (unsigned)cB[j]) * 16u;

        int4 pa[3][2], pb[3][4];
        #pragma unroll
        for (int s = 0; s < 3; ++s) {
            #pragma unroll
            for (int i = 0; i < 2; ++i) { pa[s][i] = *(const int4*)(A4 + fA[i]); fA[i] += strA; }
            #pragma unroll
            for (int j = 0; j < 4; ++j) { pb[s][j] = *(const int4*)(B4 + fB[j]); fB[j] += strB; }
        }

        unsigned sstrA = 4u * (unsigned)M, sstrB = 4u * (unsigned)N;
        unsigned sA[2], sB[4];
        unsigned psa[2][2], psb[2][4];
        #pragma unroll
        for (int i = 0; i < 2; ++i) {
            sA[i] = (unsigned)rA[i] * 4u;
            psa[0][i] = *(const unsigned*)(SaT + sA[i]);
            psa[1][i] = *(const unsigned*)(SaT + sA[i] + sstrA);
            sA[i] += 2 * sstrA;
        }
        #pragma unroll
        for (int j = 0; j < 4; ++j) {
            sB[j] = (unsigned)cB[j] * 4u;
            psb[0][j] = *(const unsigned*)(SbT + sB[j]);
            psb[1][j] = *(const unsigned*)(SbT + sB[j] + sstrB);
            sB[j] += 2 * sstrB;
        }

        // unroll 12 = lcm(slot period 3, scale period 4) so all indices are static
        #pragma unroll 12
        for (int u = 0; u < 48; ++u) {
            int sl = u % 3, wsl = (u >> 1) & 1;
            int sh = 8 * ((u & 1) * 2 + lh);
            int sa[2], sb[4];
            #pragma unroll
            for (int i = 0; i < 2; ++i) sa[i] = (int)((psa[wsl][i] >> sh) & 255);
            #pragma unroll
            for (int j = 0; j < 4; ++j) sb[j] = (int)((psb[wsl][j] >> sh) & 255);
            intx8 Afr[2], Bfr[4];
            #pragma unroll
            for (int i = 0; i < 2; ++i)
                Afr[i] = (intx8){ pa[sl][i].x, pa[sl][i].y, pa[sl][i].z, pa[sl][i].w, 0, 0, 0, 0 };
            #pragma unroll
            for (int j = 0; j < 4; ++j)
                Bfr[j] = (intx8){ pb[sl][j].x, pb[sl][j].y, pb[sl][j].z, pb[sl][j].w, 0, 0, 0, 0 };
            #pragma unroll
            for (int i = 0; i < 2; ++i)
                #pragma unroll
                for (int j = 0; j < 4; ++j)
                    acc[i][j] = __builtin_amdgcn_mfma_scale_f32_32x32x64_f8f6f4(
                        Afr[i], Bfr[j], acc[i][j], 4, 4, 0, sa[i], 0, sb[j]);
            // prefetch step u+3 into the slot just consumed (strays land in the
            // next workspace region; values never used)
            #pragma unroll
            for (int i = 0; i < 2; ++i) { pa[sl][i] = *(const int4*)(A4 + fA[i]); fA[i] += strA; }
            #pragma unroll
            for (int j = 0; j < 4; ++j) { pb[sl][j] = *(const int4*)(B4 + fB[j]); fB[j] += strB; }
            if (u & 1) {   // after second consume of this scale word, fetch up+2
                #pragma unroll
                for (int i = 0; i < 2; ++i) { psa[wsl][i] = *(const unsigned*)(SaT + sA[i]); sA[i] += sstrA; }
                #pragma unroll
                for (int j = 0; j < 4; ++j) { psb[wsl][j] = *(const unsigned*)(SbT + sB[j]); sB[j] += sstrB; }
            }
        }
    }

    // ================= fp6 (fmt 3): 12 steps of K=64, depth-2 pipeline =================
    {
        unsigned str6A = 48u * (unsigned)M, str6B = 48u * (unsigned)N;
        unsigned ss4A = 4u * (unsigned)M, ss4B = 4u * (unsigned)N;
        unsigned gA[2], gB[4], zA[2], zB[4];
        #pragma unroll
        for (int i = 0; i < 2; ++i) {
            gA[i] = ((unsigned)lh * M + (unsigned)rA[i]) * 24u;
            zA[i] = (24u * (unsigned)M + (unsigned)rA[i]) * 4u;
        }
        #pragma unroll
        for (int j = 0; j < 4; ++j) {
            gB[j] = ((unsigned)lh * N + (unsigned)cB[j]) * 24u;
            zB[j] = (24u * (unsigned)N + (unsigned)cB[j]) * 4u;
        }

        int2 qa[2][2][3], qb[2][4][3];
        unsigned p6a[2][2], p6b[2][4];
        #pragma unroll
        for (int s = 0; s < 2; ++s) {
            #pragma unroll
            for (int i = 0; i < 2; ++i) {
                const unsigned char* p = A6 + gA[i];
                qa[s][i][0] = *(const int2*)(p); qa[s][i][1] = *(const int2*)(p + 8); qa[s][i][2] = *(const int2*)(p + 16);
                p6a[s][i] = *(const unsigned*)(SaT + zA[i]);
                gA[i] += str6A; zA[i] += ss4A;
            }
            #pragma unroll
            for (int j = 0; j < 4; ++j) {
                const unsigned char* p = B6 + gB[j];
                qb[s][j][0] = *(const int2*)(p); qb[s][j][1] = *(const int2*)(p + 8); qb[s][j][2] = *(const int2*)(p + 16);
                p6b[s][j] = *(const unsigned*)(SbT + zB[j]);
                gB[j] += str6B; zB[j] += ss4B;
            }
        }
        int sh6 = 8 * lh;
        #pragma unroll 2
        for (int v = 0; v < 10; ++v) {
            int sl = v & 1;
            int sa[2], sb[4];
            #pragma unroll
            for (int i = 0; i < 2; ++i) sa[i] = (int)((p6a[sl][i] >> sh6) & 255);
            #pragma unroll
            for (int j = 0; j < 4; ++j) sb[j] = (int)((p6b[sl][j] >> sh6) & 255);
            intx8 Afr[2], Bfr[4];
            #pragma unroll
            for (int i = 0; i < 2; ++i)
                Afr[i] = (intx8){ qa[sl][i][0].x, qa[sl][i][0].y, qa[sl][i][1].x, qa[sl][i][1].y, qa[sl][i][2].x, qa[sl][i][2].y, 0, 0 };
            #pragma unroll
            for (int j = 0; j < 4; ++j)
                Bfr[j] = (intx8){ qb[sl][j][0].x, qb[sl][j][0].y, qb[sl][j][1].x, qb[sl][j][1].y, qb[sl][j][2].x, qb[sl][j][2].y, 0, 0 };
            #pragma unroll
            for (int i = 0; i < 2; ++i)
                #pragma unroll
                for (int j = 0; j < 4; ++j)
                    acc[i][j] = __builtin_amdgcn_mfma_scale_f32_32x32x64_f8f6f4(
                        Afr[i], Bfr[j], acc[i][j], 3, 3, 0, sa[i], 0, sb[j]);
            {   // prefetch v+2 into slot just consumed (v+2 <= 11: fully in-bounds)
                #pragma unroll
                for (int i = 0; i < 2; ++i) {
                    const unsigned char* p = A6 + gA[i];
                    qa[sl][i][0] = *(const int2*)(p); qa[sl][i][1] = *(const int2*)(p + 8); qa[sl][i][2] = *(const int2*)(p + 16);
                    p6a[sl][i] = *(const unsigned*)(SaT + zA[i]);
                    gA[i] += str6A; zA[i] += ss4A;
                }
                #pragma unroll
                for (int j = 0; j < 4; ++j) {
                    const unsigned char* p = B6 + gB[j];
                    qb[sl][j][0] = *(const int2*)(p); qb[sl][j][1] = *(const int2*)(p + 8); qb[sl][j][2] = *(const int2*)(p + 16);
                    p6b[sl][j] = *(const unsigned*)(SbT + zB[j]);
                    gB[j] += str6B; zB[j] += ss4B;
                }
            }
        }
        #pragma unroll
        for (int v = 10; v < 12; ++v) {   // peeled tail: consume-only (no stray scale reads)
            int sl = v & 1;
            int sa[2], sb[4];
            #pragma unroll
            for (int i = 0; i < 2; ++i) sa[i] = (int)((p6a[sl][i] >> sh6) & 255);
            #pragma unroll
            for (int j = 0; j < 4; ++j) sb[j] = (int)((p6b[sl][j] >> sh6) & 255);
            intx8 Afr[2], Bfr[4];
            #pragma unroll
            for (int i = 0; i < 2; ++i)
                Afr[i] = (intx8){ qa[sl][i][0].x, qa[sl][i][0].y, qa[sl][i][1].x, qa[sl][i][1].y, qa[sl][i][2].x, qa[sl][i][2].y, 0, 0 };
            #pragma unroll
            for (int j = 0; j < 4; ++j)
                Bfr[j] = (intx8){ qb[sl][j][0].x, qb[sl][j][0].y, qb[sl][j][1].x, qb[sl][j][1].y, qb[sl][j][2].x, qb[sl][j][2].y, 0, 0 };
            #pragma unroll
            for (int i = 0; i < 2; ++i)
                #pragma unroll
                for (int j = 0; j < 4; ++j)
                    acc[i][j] = __builtin_amdgcn_mfma_scale_f32_32x32x64_f8f6f4(
                        Afr[i], Bfr[j], acc[i][j], 3, 3, 0, sa[i], 0, sb[j]);
        }
    }

    // ================= fp8 as bf16: 16 steps of K=16, depth-2 pipeline =================
    {
        unsigned str8A = 32u * (unsigned)M, str8B = 32u * (unsigned)N;
        const unsigned char* A8b = (const unsigned char*)A8;
        const unsigned char* B8b = (const unsigned char*)B8;
        unsigned hA[2], hB[4];
        #pragma unroll
        for (int i = 0; i < 2; ++i) hA[i] = ((unsigned)lh * M + (unsigned)rA[i]) * 16u;
        #pragma unroll
        for (int j = 0; j < 4; ++j) hB[j] = ((unsigned)lh * N + (unsigned)cB[j]) * 16u;
        short8 ra[2][2], rb[2][4];
        #pragma unroll
        for (int s = 0; s < 2; ++s) {
            #pragma unroll
            for (int i = 0; i < 2; ++i) { ra[s][i] = *(const short8*)(A8b + hA[i]); hA[i] += str8A; }
            #pragma unroll
            for (int j = 0; j < 4; ++j) { rb[s][j] = *(const short8*)(B8b + hB[j]); hB[j] += str8B; }
        }
        #pragma unroll 2
        for (int q = 0; q < 16; ++q) {
            int sl = q & 1;
            #pragma unroll
            for (int i = 0; i < 2; ++i)
                #pragma unroll
                for (int j = 0; j < 4; ++j)
                    acc[i][j] = __builtin_amdgcn_mfma_f32_32x32x16_bf16(ra[sl][i], rb[sl][j], acc[i][j], 0, 0, 0);
            // prefetch q+2 (tail strays stay inside A8->B8 / B8->SaT regions)
            #pragma unroll
            for (int i = 0; i < 2; ++i) { ra[sl][i] = *(const short8*)(A8b + hA[i]); hA[i] += str8A; }
            #pragma unroll
            for (int j = 0; j < 4; ++j) { rb[sl][j] = *(const short8*)(B8b + hB[j]); hB[j] += str8B; }
        }
    }

    // epilogue: 32x32 C/D layout col=lane&31, row=(r&3)+8*(r>>2)+4*lh (m74/m101-verified)
    #pragma unroll
    for (int i = 0; i < 2; i++)
        #pragma unroll
        for (int j = 0; j < 4; j++) {
            int col = bn * 256 + wn + j * 32 + lr;
            float bv = bias[col];
            #pragma unroll
            for (int r = 0; r < 16; r++) {
                int row = bm * 128 + wm + i * 32 + (r & 3) + 8 * (r >> 2) + 4 * lh;
                C[(size_t)row * N + col] = acc[i][j][r] + bv;
            }
        }
}

extern "C" void kernel_launch(void* const* d_in, const int* in_sizes, int n_in,
                              void* d_out, int out_size, void* d_ws, size_t ws_size,
                              hipStream_t stream) {
    const int* AN   = (const int*)d_in[0];
    const int* ASs  = (const int*)d_in[1];
    const int* AO   = (const int*)d_in[2];
    const int* SFAN = (const int*)d_in[3];
    const int* SFAS = (const int*)d_in[4];
    const int* SFAO = (const int*)d_in[5];
    const int* BN   = (const int*)d_in[6];
    const int* BS   = (const int*)d_in[7];
    const int* BO   = (const int*)d_in[8];
    const int* SFBN = (const int*)d_in[9];
    const int* SFBS = (const int*)d_in[10];
    const int* SFBO = (const int*)d_in[11];
    const float* bias = (const float*)d_in[12];

    int M = in_sizes[0] / 1536;
    int N = in_sizes[6] / 1536;

    unsigned char* ws = (unsigned char*)d_ws;
    size_t o = 0;
    unsigned char*  A4c = ws + o;                    o += (size_t)M * 1536;
    unsigned char*  B4c = ws + o;                    o += (size_t)N * 1536;
    unsigned char*  A6c = ws + o;                    o += (size_t)M * 576;
    unsigned char*  B6c = ws + o;                    o += (size_t)N * 576;
    unsigned short* A8d = (unsigned short*)(ws + o); o += (size_t)M * 512;
    unsigned short* B8d = (unsigned short*)(ws + o); o += (size_t)N * 512;
    unsigned char*  SaT = ws + o;                    o += (size_t)36 * M * 4;
    unsigned char*  SbT = ws + o;                    o += (size_t)36 * N * 4;

    pack_lds<<<(M >> 6) * 8, 256, 0, stream>>>(AN, ASs, AO, SFAN, SFAS, SFAO,
                                               A4c, A6c, A8d, SaT, M);
    pack_lds<<<(N >> 6) * 8, 256, 0, stream>>>(BN, BS, BO, SFBN, SFBS, SFBO,
                                               B4c, B6c, B8d, SbT, N);

    dim3 grid(N / 256, M / 128);
    gemm_mx<<<grid, 256, 0, stream>>>(A4c, B4c, A6c, B6c, A8d, B8d,
                                      SaT, SbT, bias, (float*)d_out, M, N);
}

// Round 7
// 234.010 us; speedup vs baseline: 1.2445x; 1.2445x over previous
//
#include <hip/hip_runtime.h>

typedef short short8 __attribute__((ext_vector_type(8)));
typedef int   intx8  __attribute__((ext_vector_type(8)));
typedef float floatx16 __attribute__((ext_vector_type(16)));

__device__ __forceinline__ unsigned pk4(int a, int b, int c, int d) {
    return (a & 255) | ((b & 255) << 8) | ((c & 255) << 16) | ((unsigned)(d & 255) << 24);
}

// E4M3 code + E8M0 scale exponent (esf = sf-127) -> bf16 bits. Exact, integer-only.
// NaN code (e=15,m=7) decodes to 480*2^esf like the reference (fp8 can't use the
// HW f8f6f4 path: HW would produce NaN).
__device__ __forceinline__ unsigned dec8bf(int c, int esf) {
    int s = (c & 128) << 8;
    int e = (c >> 3) & 15, m = c & 7;
    int rn = s | ((e + 120 + esf) << 7) | (m << 4);                 // normal: (1+m/8)*2^(e-7)
    int nb = (m >= 4) ? 2 : ((m >= 2) ? 1 : 0);                     // floor(log2 m)
    int rs = m ? (s | ((nb + 118 + esf) << 7) | ((m << (7 - nb)) & 0x7F)) : s;  // subnormal m*2^-9
    return (unsigned)(e ? rn : rs);
}

// ---- prepass (r4 version, unchanged: fully coalesced both sides via LDS stage).
__global__ __launch_bounds__(256) void pack_lds(
    const int* __restrict__ Pn, const int* __restrict__ Ps, const int* __restrict__ Po,
    const int* __restrict__ Sn, const int* __restrict__ Ss, const int* __restrict__ So,
    unsigned char* __restrict__ C4, unsigned char* __restrict__ C6,
    unsigned short* __restrict__ C8, unsigned char* __restrict__ St, int R)
{
    __shared__ unsigned lds[9216];                 // 36 KB, max section (fp6)
    int t = threadIdx.x, b = blockIdx.x, per = R >> 6;
    if (b < 4 * per) {                             // ---- fp4: 64 rows x 24 chunks
        int jg = b / per, rb = b - jg * per, r0 = rb << 6;
        #pragma unroll
        for (int i = 0; i < 24; ++i) {
            int idx = i * 256 + t, row = idx / 96, q4 = idx - row * 96;
            int4 v = *(const int4*)(Pn + (size_t)(r0 + row) * 1536 + jg * 384 + q4 * 4);
            lds[row * 96 + q4] = pk4(v.x, v.y, v.z, v.w);
        }
        __syncthreads();
        #pragma unroll
        for (int i = 0; i < 6; ++i) {
            int idx = i * 256 + t, j = idx >> 6, row = idx & 63;
            uint4 v = *(uint4*)&lds[row * 96 + j * 4];
            *(uint4*)(C4 + ((size_t)(jg * 24 + j) * R + r0 + row) * 16) = v;
        }
    } else if (b < 5 * per) {                      // ---- fp6
        int rb = b - 4 * per, r0 = rb << 6;
        #pragma unroll
        for (int i = 0; i < 36; ++i) {
            int idx = i * 256 + t, row = idx / 144, q4 = idx - row * 144;
            int4 v = *(const int4*)(Ps + (size_t)(r0 + row) * 576 + q4 * 4);
            lds[row * 144 + q4] = pk4(v.x, v.y, v.z, v.w);
        }
        __syncthreads();
        #pragma unroll
        for (int i = 0; i < 18; ++i) {
            int idx = i * 256 + t, seg = idx / 192, off = idx - seg * 192;
            int row = off / 3, m3 = off - row * 3;
            int w0 = row * 144 + seg * 6 + m3 * 2;
            int2 v = { (int)lds[w0], (int)lds[w0 + 1] };
            *(int2*)(C6 + ((size_t)seg * R + r0) * 24 + (size_t)off * 8) = v;
        }
    } else if (b < 6 * per) {                      // ---- fp8: decode+scale to bf16
        int rb = b - 5 * per, r0 = rb << 6;
        #pragma unroll
        for (int i = 0; i < 16; ++i) {
            int idx = i * 256 + t, row = idx >> 6, q4 = idx & 63;
            int4 c = *(const int4*)(Po + (size_t)(r0 + row) * 256 + q4 * 4);
            int e = So[(size_t)(r0 + row) * 8 + (q4 >> 3)] - 127;
            lds[row * 128 + q4 * 2]     = dec8bf(c.x & 255, e) | (dec8bf(c.y & 255, e) << 16);
            lds[row * 128 + q4 * 2 + 1] = dec8bf(c.z & 255, e) | (dec8bf(c.w & 255, e) << 16);
        }
        __syncthreads();
        #pragma unroll
        for (int i = 0; i < 8; ++i) {
            int idx = i * 256 + t, seg = idx >> 6, row = idx & 63;
            uint4 v = *(uint4*)&lds[row * 128 + seg * 4];
            *(uint4*)((unsigned char*)C8 + ((size_t)seg * R + r0 + row) * 16) = v;
        }
    } else if (b < 7 * per) {                      // ---- fp4 scale quads
        int rb = b - 6 * per, r0 = rb << 6;
        #pragma unroll
        for (int i = 0; i < 6; ++i) {
            int idx = i * 256 + t, row = idx / 24, q4 = idx - row * 24;
            int4 v = *(const int4*)(Sn + (size_t)(r0 + row) * 96 + q4 * 4);
            lds[row * 24 + q4] = pk4(v.x, v.y, v.z, v.w);
        }
        __syncthreads();
        #pragma unroll
        for (int i = 0; i < 6; ++i) {
            int idx = i * 256 + t, seg = idx >> 6, row = idx & 63;
            *(unsigned*)(St + ((size_t)seg * R + r0 + row) * 4) = lds[row * 24 + seg];
        }
    } else {                                       // ---- fp6 scale pairs
        int rb = b - 7 * per, r0 = rb << 6;
        #pragma unroll
        for (int i = 0; i < 3; ++i) {
            int idx = i * 256 + t, row = idx / 12, b2 = idx - row * 12;
            int2 v = *(const int2*)(Ss + (size_t)(r0 + row) * 24 + b2 * 2);
            lds[row * 12 + b2] = (unsigned)((v.x & 255) | ((v.y & 255) << 8));
        }
        __syncthreads();
        #pragma unroll
        for (int i = 0; i < 3; ++i) {
            int idx = i * 256 + t, seg = idx >> 6, row = idx & 63;
            *(unsigned*)(St + ((size_t)(24 + seg) * R + r0 + row) * 4) = lds[row * 12 + seg];
        }
    }
}

// ---- barrier-free direct-load MX GEMM v7: r1 structure (64x64 wave tile,
// (256,2), register pipelines) with DEEPER pipelines -- the only lever with
// verified-safe register headroom (r1 peaked at 100 arch VGPR of the 192
// available beside the 64 AGPR acc).
//   fp4: depth-6 (96 frag regs), unroll 12 so prefetch distance = half the
//        unrolled body (better static scheduling than r1's distance==body).
//   fp6: depth-3.  fp8: depth-3, fully unrolled.
// Ledger: (256,3) spills (r3), per-step-barrier LDS staging locksteps (r5),
// XCD swizzle null (r4), 64x128 tile spills (r6). Tail prefetch strays are
// bounded reads into the adjacent workspace region (A4->B4->A6, A8->B8->SaT;
// <=0.7MB, values never used); fp6 tail (v=9..11) peeled, fully in-bounds.
__global__ __launch_bounds__(256, 2) void gemm_mx(
    const unsigned char* __restrict__ A4, const unsigned char* __restrict__ B4,
    const unsigned char* __restrict__ A6, const unsigned char* __restrict__ B6,
    const unsigned short* __restrict__ A8, const unsigned short* __restrict__ B8,
    const unsigned char* __restrict__ SaT, const unsigned char* __restrict__ SbT,
    const float* __restrict__ bias, float* __restrict__ C, int M, int N)
{
    int tid = threadIdx.x, w = tid >> 6, l = tid & 63;
    int bm = blockIdx.y, bn = blockIdx.x;
    int wm = (w >> 1) * 64, wn = (w & 1) * 64;
    int lr = l & 31, lh = l >> 5;

    floatx16 acc[2][2] = {};

    int rA[2] = { bm * 128 + wm + lr, bm * 128 + wm + 32 + lr };
    int cB[2] = { bn * 128 + wn + lr, bn * 128 + wn + 32 + lr };

    // ================= fp4 (fmt 4): 48 steps of K=64, depth-6 pipeline =================
    {
        unsigned strA = 32u * (unsigned)M, strB = 32u * (unsigned)N;
        unsigned fA0 = ((unsigned)lh * M + (unsigned)rA[0]) * 16u;
        unsigned fA1 = ((unsigned)lh * M + (unsigned)rA[1]) * 16u;
        unsigned fB0 = ((unsigned)lh * N + (unsigned)cB[0]) * 16u;
        unsigned fB1 = ((unsigned)lh * N + (unsigned)cB[1]) * 16u;

        int4 pa[6][2], pb[6][2];
        #pragma unroll
        for (int s = 0; s < 6; ++s) {
            pa[s][0] = *(const int4*)(A4 + fA0); pa[s][1] = *(const int4*)(A4 + fA1);
            pb[s][0] = *(const int4*)(B4 + fB0); pb[s][1] = *(const int4*)(B4 + fB1);
            fA0 += strA; fA1 += strA; fB0 += strB; fB1 += strB;
        }

        unsigned sstrA = 4u * (unsigned)M, sstrB = 4u * (unsigned)N;
        unsigned sA0 = (unsigned)rA[0] * 4u, sA1 = (unsigned)rA[1] * 4u;
        unsigned sB0 = (unsigned)cB[0] * 4u, sB1 = (unsigned)cB[1] * 4u;
        unsigned psa[2][2], psb[2][2];
        psa[0][0] = *(const unsigned*)(SaT + sA0);         psa[0][1] = *(const unsigned*)(SaT + sA1);
        psb[0][0] = *(const unsigned*)(SbT + sB0);         psb[0][1] = *(const unsigned*)(SbT + sB1);
        psa[1][0] = *(const unsigned*)(SaT + sA0 + sstrA); psa[1][1] = *(const unsigned*)(SaT + sA1 + sstrA);
        psb[1][0] = *(const unsigned*)(SbT + sB0 + sstrB); psb[1][1] = *(const unsigned*)(SbT + sB1 + sstrB);
        sA0 += 2 * sstrA; sA1 += 2 * sstrA; sB0 += 2 * sstrB; sB1 += 2 * sstrB;  // next: up=2

        // unroll 12 = lcm(slot period 6, scale period 4): all indices static,
        // prefetch->consume distance (6 steps) = half the unrolled body.
        #pragma unroll 12
        for (int u = 0; u < 48; ++u) {
            int sl = u % 6, wsl = (u >> 1) & 1;
            int sh = 8 * ((u & 1) * 2 + lh);
            int sa0 = (int)((psa[wsl][0] >> sh) & 255), sa1 = (int)((psa[wsl][1] >> sh) & 255);
            int sb0 = (int)((psb[wsl][0] >> sh) & 255), sb1 = (int)((psb[wsl][1] >> sh) & 255);
            intx8 A0 = (intx8){ pa[sl][0].x, pa[sl][0].y, pa[sl][0].z, pa[sl][0].w, 0, 0, 0, 0 };
            intx8 A1 = (intx8){ pa[sl][1].x, pa[sl][1].y, pa[sl][1].z, pa[sl][1].w, 0, 0, 0, 0 };
            intx8 B0 = (intx8){ pb[sl][0].x, pb[sl][0].y, pb[sl][0].z, pb[sl][0].w, 0, 0, 0, 0 };
            intx8 B1 = (intx8){ pb[sl][1].x, pb[sl][1].y, pb[sl][1].z, pb[sl][1].w, 0, 0, 0, 0 };
            acc[0][0] = __builtin_amdgcn_mfma_scale_f32_32x32x64_f8f6f4(A0, B0, acc[0][0], 4, 4, 0, sa0, 0, sb0);
            acc[0][1] = __builtin_amdgcn_mfma_scale_f32_32x32x64_f8f6f4(A0, B1, acc[0][1], 4, 4, 0, sa0, 0, sb1);
            acc[1][0] = __builtin_amdgcn_mfma_scale_f32_32x32x64_f8f6f4(A1, B0, acc[1][0], 4, 4, 0, sa1, 0, sb0);
            acc[1][1] = __builtin_amdgcn_mfma_scale_f32_32x32x64_f8f6f4(A1, B1, acc[1][1], 4, 4, 0, sa1, 0, sb1);
            // prefetch step u+6 into the slot just consumed (strays land in the
            // next workspace region, <=0.7MB past the section; values never used)
            pa[sl][0] = *(const int4*)(A4 + fA0); pa[sl][1] = *(const int4*)(A4 + fA1);
            pb[sl][0] = *(const int4*)(B4 + fB0); pb[sl][1] = *(const int4*)(B4 + fB1);
            fA0 += strA; fA1 += strA; fB0 += strB; fB1 += strB;
            if (u & 1) {   // after second consume of this scale word, fetch up+2 (3 steps ahead)
                psa[wsl][0] = *(const unsigned*)(SaT + sA0); psa[wsl][1] = *(const unsigned*)(SaT + sA1);
                psb[wsl][0] = *(const unsigned*)(SbT + sB0); psb[wsl][1] = *(const unsigned*)(SbT + sB1);
                sA0 += sstrA; sA1 += sstrA; sB0 += sstrB; sB1 += sstrB;
            }
        }
    }

    // ================= fp6 (fmt 3): 12 steps of K=64, depth-3 pipeline =================
    {
        unsigned str6A = 48u * (unsigned)M, str6B = 48u * (unsigned)N;
        unsigned gA0 = ((unsigned)lh * M + (unsigned)rA[0]) * 24u;
        unsigned gA1 = ((unsigned)lh * M + (unsigned)rA[1]) * 24u;
        unsigned gB0 = ((unsigned)lh * N + (unsigned)cB[0]) * 24u;
        unsigned gB1 = ((unsigned)lh * N + (unsigned)cB[1]) * 24u;
        unsigned ss4A = 4u * (unsigned)M, ss4B = 4u * (unsigned)N;
        unsigned zA0 = (24u * (unsigned)M + (unsigned)rA[0]) * 4u;
        unsigned zA1 = (24u * (unsigned)M + (unsigned)rA[1]) * 4u;
        unsigned zB0 = (24u * (unsigned)N + (unsigned)cB[0]) * 4u;
        unsigned zB1 = (24u * (unsigned)N + (unsigned)cB[1]) * 4u;

        int2 qa[3][2][3], qb[3][2][3];
        unsigned p6a[3][2], p6b[3][2];
        #pragma unroll
        for (int s = 0; s < 3; ++s) {
            const unsigned char *a0 = A6 + gA0, *a1 = A6 + gA1, *b0 = B6 + gB0, *b1 = B6 + gB1;
            qa[s][0][0] = *(const int2*)(a0); qa[s][0][1] = *(const int2*)(a0 + 8); qa[s][0][2] = *(const int2*)(a0 + 16);
            qa[s][1][0] = *(const int2*)(a1); qa[s][1][1] = *(const int2*)(a1 + 8); qa[s][1][2] = *(const int2*)(a1 + 16);
            qb[s][0][0] = *(const int2*)(b0); qb[s][0][1] = *(const int2*)(b0 + 8); qb[s][0][2] = *(const int2*)(b0 + 16);
            qb[s][1][0] = *(const int2*)(b1); qb[s][1][1] = *(const int2*)(b1 + 8); qb[s][1][2] = *(const int2*)(b1 + 16);
            p6a[s][0] = *(const unsigned*)(SaT + zA0); p6a[s][1] = *(const unsigned*)(SaT + zA1);
            p6b[s][0] = *(const unsigned*)(SbT + zB0); p6b[s][1] = *(const unsigned*)(SbT + zB1);
            gA0 += str6A; gA1 += str6A; gB0 += str6B; gB1 += str6B;
            zA0 += ss4A; zA1 += ss4A; zB0 += ss4B; zB1 += ss4B;
        }
        int sh6 = 8 * lh;
        #pragma unroll 3
        for (int v = 0; v < 9; ++v) {
            int sl = v % 3;
            int sa0 = (int)((p6a[sl][0] >> sh6) & 255), sa1 = (int)((p6a[sl][1] >> sh6) & 255);
            int sb0 = (int)((p6b[sl][0] >> sh6) & 255), sb1 = (int)((p6b[sl][1] >> sh6) & 255);
            intx8 A0 = (intx8){ qa[sl][0][0].x, qa[sl][0][0].y, qa[sl][0][1].x, qa[sl][0][1].y, qa[sl][0][2].x, qa[sl][0][2].y, 0, 0 };
            intx8 A1 = (intx8){ qa[sl][1][0].x, qa[sl][1][0].y, qa[sl][1][1].x, qa[sl][1][1].y, qa[sl][1][2].x, qa[sl][1][2].y, 0, 0 };
            intx8 B0 = (intx8){ qb[sl][0][0].x, qb[sl][0][0].y, qb[sl][0][1].x, qb[sl][0][1].y, qb[sl][0][2].x, qb[sl][0][2].y, 0, 0 };
            intx8 B1 = (intx8){ qb[sl][1][0].x, qb[sl][1][0].y, qb[sl][1][1].x, qb[sl][1][1].y, qb[sl][1][2].x, qb[sl][1][2].y, 0, 0 };
            acc[0][0] = __builtin_amdgcn_mfma_scale_f32_32x32x64_f8f6f4(A0, B0, acc[0][0], 3, 3, 0, sa0, 0, sb0);
            acc[0][1] = __builtin_amdgcn_mfma_scale_f32_32x32x64_f8f6f4(A0, B1, acc[0][1], 3, 3, 0, sa0, 0, sb1);
            acc[1][0] = __builtin_amdgcn_mfma_scale_f32_32x32x64_f8f6f4(A1, B0, acc[1][0], 3, 3, 0, sa1, 0, sb0);
            acc[1][1] = __builtin_amdgcn_mfma_scale_f32_32x32x64_f8f6f4(A1, B1, acc[1][1], 3, 3, 0, sa1, 0, sb1);
            {   // prefetch v+3 into slot just consumed (v+3 <= 11: fully in-bounds)
                const unsigned char *a0 = A6 + gA0, *a1 = A6 + gA1, *b0 = B6 + gB0, *b1 = B6 + gB1;
                qa[sl][0][0] = *(const int2*)(a0); qa[sl][0][1] = *(const int2*)(a0 + 8); qa[sl][0][2] = *(const int2*)(a0 + 16);
                qa[sl][1][0] = *(const int2*)(a1); qa[sl][1][1] = *(const int2*)(a1 + 8); qa[sl][1][2] = *(const int2*)(a1 + 16);
                qb[sl][0][0] = *(const int2*)(b0); qb[sl][0][1] = *(const int2*)(b0 + 8); qb[sl][0][2] = *(const int2*)(b0 + 16);
                qb[sl][1][0] = *(const int2*)(b1); qb[sl][1][1] = *(const int2*)(b1 + 8); qb[sl][1][2] = *(const int2*)(b1 + 16);
                p6a[sl][0] = *(const unsigned*)(SaT + zA0); p6a[sl][1] = *(const unsigned*)(SaT + zA1);
                p6b[sl][0] = *(const unsigned*)(SbT + zB0); p6b[sl][1] = *(const unsigned*)(SbT + zB1);
                gA0 += str6A; gA1 += str6A; gB0 += str6B; gB1 += str6B;
                zA0 += ss4A; zA1 += ss4A; zB0 += ss4B; zB1 += ss4B;
            }
        }
        #pragma unroll
        for (int v = 9; v < 12; ++v) {    // peeled tail: consume-only (no stray scale reads)
            int sl = v % 3;
            int sa0 = (int)((p6a[sl][0] >> sh6) & 255), sa1 = (int)((p6a[sl][1] >> sh6) & 255);
            int sb0 = (int)((p6b[sl][0] >> sh6) & 255), sb1 = (int)((p6b[sl][1] >> sh6) & 255);
            intx8 A0 = (intx8){ qa[sl][0][0].x, qa[sl][0][0].y, qa[sl][0][1].x, qa[sl][0][1].y, qa[sl][0][2].x, qa[sl][0][2].y, 0, 0 };
            intx8 A1 = (intx8){ qa[sl][1][0].x, qa[sl][1][0].y, qa[sl][1][1].x, qa[sl][1][1].y, qa[sl][1][2].x, qa[sl][1][2].y, 0, 0 };
            intx8 B0 = (intx8){ qb[sl][0][0].x, qb[sl][0][0].y, qb[sl][0][1].x, qb[sl][0][1].y, qb[sl][0][2].x, qb[sl][0][2].y, 0, 0 };
            intx8 B1 = (intx8){ qb[sl][1][0].x, qb[sl][1][0].y, qb[sl][1][1].x, qb[sl][1][1].y, qb[sl][1][2].x, qb[sl][1][2].y, 0, 0 };
            acc[0][0] = __builtin_amdgcn_mfma_scale_f32_32x32x64_f8f6f4(A0, B0, acc[0][0], 3, 3, 0, sa0, 0, sb0);
            acc[0][1] = __builtin_amdgcn_mfma_scale_f32_32x32x64_f8f6f4(A0, B1, acc[0][1], 3, 3, 0, sa0, 0, sb1);
            acc[1][0] = __builtin_amdgcn_mfma_scale_f32_32x32x64_f8f6f4(A1, B0, acc[1][0], 3, 3, 0, sa1, 0, sb0);
            acc[1][1] = __builtin_amdgcn_mfma_scale_f32_32x32x64_f8f6f4(A1, B1, acc[1][1], 3, 3, 0, sa1, 0, sb1);
        }
    }

    // ================= fp8 as bf16: 16 steps of K=16, depth-3 pipeline =================
    {
        unsigned str8A = 32u * (unsigned)M, str8B = 32u * (unsigned)N;
        const unsigned char* A8b = (const unsigned char*)A8;
        const unsigned char* B8b = (const unsigned char*)B8;
        unsigned hA0 = ((unsigned)lh * M + (unsigned)rA[0]) * 16u;
        unsigned hA1 = ((unsigned)lh * M + (unsigned)rA[1]) * 16u;
        unsigned hB0 = ((unsigned)lh * N + (unsigned)cB[0]) * 16u;
        unsigned hB1 = ((unsigned)lh * N + (unsigned)cB[1]) * 16u;
        short8 ra[3][2], rb[3][2];
        #pragma unroll
        for (int s = 0; s < 3; ++s) {
            ra[s][0] = *(const short8*)(A8b + hA0); ra[s][1] = *(const short8*)(A8b + hA1);
            rb[s][0] = *(const short8*)(B8b + hB0); rb[s][1] = *(const short8*)(B8b + hB1);
            hA0 += str8A; hA1 += str8A; hB0 += str8B; hB1 += str8B;
        }
        #pragma unroll
        for (int q = 0; q < 16; ++q) {
            int sl = q % 3;
            acc[0][0] = __builtin_amdgcn_mfma_f32_32x32x16_bf16(ra[sl][0], rb[sl][0], acc[0][0], 0, 0, 0);
            acc[0][1] = __builtin_amdgcn_mfma_f32_32x32x16_bf16(ra[sl][0], rb[sl][1], acc[0][1], 0, 0, 0);
            acc[1][0] = __builtin_amdgcn_mfma_f32_32x32x16_bf16(ra[sl][1], rb[sl][0], acc[1][0], 0, 0, 0);
            acc[1][1] = __builtin_amdgcn_mfma_f32_32x32x16_bf16(ra[sl][1], rb[sl][1], acc[1][1], 0, 0, 0);
            // prefetch q+3 (tail strays stay inside A8->B8 / B8->SaT regions, <=320KB)
            ra[sl][0] = *(const short8*)(A8b + hA0); ra[sl][1] = *(const short8*)(A8b + hA1);
            rb[sl][0] = *(const short8*)(B8b + hB0); rb[sl][1] = *(const short8*)(B8b + hB1);
            hA0 += str8A; hA1 += str8A; hB0 += str8B; hB1 += str8B;
        }
    }

    // epilogue: 32x32 C/D layout col=lane&31, row=(r&3)+8*(r>>2)+4*lh (m74/m101-verified)
    #pragma unroll
    for (int i = 0; i < 2; i++)
        #pragma unroll
        for (int j = 0; j < 2; j++) {
            int col = bn * 128 + wn + j * 32 + lr;
            float bv = bias[col];
            #pragma unroll
            for (int r = 0; r < 16; r++) {
                int row = bm * 128 + wm + i * 32 + (r & 3) + 8 * (r >> 2) + 4 * lh;
                C[(size_t)row * N + col] = acc[i][j][r] + bv;
            }
        }
}

extern "C" void kernel_launch(void* const* d_in, const int* in_sizes, int n_in,
                              void* d_out, int out_size, void* d_ws, size_t ws_size,
                              hipStream_t stream) {
    const int* AN   = (const int*)d_in[0];
    const int* ASs  = (const int*)d_in[1];
    const int* AO   = (const int*)d_in[2];
    const int* SFAN = (const int*)d_in[3];
    const int* SFAS = (const int*)d_in[4];
    const int* SFAO = (const int*)d_in[5];
    const int* BN   = (const int*)d_in[6];
    const int* BS   = (const int*)d_in[7];
    const int* BO   = (const int*)d_in[8];
    const int* SFBN = (const int*)d_in[9];
    const int* SFBS = (const int*)d_in[10];
    const int* SFBO = (const int*)d_in[11];
    const float* bias = (const float*)d_in[12];

    int M = in_sizes[0] / 1536;
    int N = in_sizes[6] / 1536;

    unsigned char* ws = (unsigned char*)d_ws;
    size_t o = 0;
    unsigned char*  A4c = ws + o;                    o += (size_t)M * 1536;
    unsigned char*  B4c = ws + o;                    o += (size_t)N * 1536;
    unsigned char*  A6c = ws + o;                    o += (size_t)M * 576;
    unsigned char*  B6c = ws + o;                    o += (size_t)N * 576;
    unsigned short* A8d = (unsigned short*)(ws + o); o += (size_t)M * 512;
    unsigned short* B8d = (unsigned short*)(ws + o); o += (size_t)N * 512;
    unsigned char*  SaT = ws + o;                    o += (size_t)36 * M * 4;
    unsigned char*  SbT = ws + o;                    o += (size_t)36 * N * 4;

    pack_lds<<<(M >> 6) * 8, 256, 0, stream>>>(AN, ASs, AO, SFAN, SFAS, SFAO,
                                               A4c, A6c, A8d, SaT, M);
    pack_lds<<<(N >> 6) * 8, 256, 0, stream>>>(BN, BS, BO, SFBN, SFBS, SFBO,
                                               B4c, B6c, B8d, SbT, N);

    dim3 grid(N / 128, M / 128);
    gemm_mx<<<grid, 256, 0, stream>>>(A4c, B4c, A6c, B6c, A8d, B8d,
                                      SaT, SbT, bias, (float*)d_out, M, N);
}

// Round 8
// 210.920 us; speedup vs baseline: 1.3808x; 1.1095x over previous
//
#include <hip/hip_runtime.h>

typedef short short8 __attribute__((ext_vector_type(8)));
typedef int   intx8  __attribute__((ext_vector_type(8)));
typedef float floatx16 __attribute__((ext_vector_type(16)));

__device__ __forceinline__ unsigned pk4(int a, int b, int c, int d) {
    return (a & 255) | ((b & 255) << 8) | ((c & 255) << 16) | ((unsigned)(d & 255) << 24);
}

// E4M3 code + E8M0 scale exponent (esf = sf-127) -> bf16 bits. Exact, integer-only.
// NaN code (e=15,m=7) decodes to 480*2^esf like the reference (fp8 can't use the
// HW f8f6f4 path: HW would produce NaN).
__device__ __forceinline__ unsigned dec8bf(int c, int esf) {
    int s = (c & 128) << 8;
    int e = (c >> 3) & 15, m = c & 7;
    int rn = s | ((e + 120 + esf) << 7) | (m << 4);                 // normal: (1+m/8)*2^(e-7)
    int nb = (m >= 4) ? 2 : ((m >= 2) ? 1 : 0);                     // floor(log2 m)
    int rs = m ? (s | ((nb + 118 + esf) << 7) | ((m << (7 - nb)) & 0x7F)) : s;  // subnormal m*2^-9
    return (unsigned)(e ? rn : rs);
}

// ---- prepass: LDS-staged repack, both global sides coalesced (r4-proven).
// Single kernel for A and B sides (saves one launch gap).
// C4 [96][R][16] : fp4 codes, chunk j = k nibbles 32j..32j+31
// C6 [24][R][24] : fp6 raw stream, window g = k 32g..32g+31
// C8 [32][R][8]  : fp8 decoded+scaled bf16, chunk j = k 8j..8j+7
// St [36][R][4]  : rows 0..23 fp4 scale quads; rows 24..35 fp6 scale pairs
__device__ __forceinline__ void pack_side_lds(
    int b, int t, unsigned* lds,
    const int* __restrict__ Pn, const int* __restrict__ Ps, const int* __restrict__ Po,
    const int* __restrict__ Sn, const int* __restrict__ Ss, const int* __restrict__ So,
    unsigned char* __restrict__ C4, unsigned char* __restrict__ C6,
    unsigned short* __restrict__ C8, unsigned char* __restrict__ St, int R)
{
    int per = R >> 6;
    if (b < 4 * per) {                             // ---- fp4: 64 rows x 24 chunks
        int jg = b / per, rb = b - jg * per, r0 = rb << 6;
        #pragma unroll
        for (int i = 0; i < 24; ++i) {
            int idx = i * 256 + t, row = idx / 96, q4 = idx - row * 96;
            int4 v = *(const int4*)(Pn + (size_t)(r0 + row) * 1536 + jg * 384 + q4 * 4);
            lds[row * 96 + q4] = pk4(v.x, v.y, v.z, v.w);
        }
        __syncthreads();
        #pragma unroll
        for (int i = 0; i < 6; ++i) {
            int idx = i * 256 + t, j = idx >> 6, row = idx & 63;
            uint4 v = *(uint4*)&lds[row * 96 + j * 4];
            *(uint4*)(C4 + ((size_t)(jg * 24 + j) * R + r0 + row) * 16) = v;
        }
    } else if (b < 5 * per) {                      // ---- fp6
        int rb = b - 4 * per, r0 = rb << 6;
        #pragma unroll
        for (int i = 0; i < 36; ++i) {
            int idx = i * 256 + t, row = idx / 144, q4 = idx - row * 144;
            int4 v = *(const int4*)(Ps + (size_t)(r0 + row) * 576 + q4 * 4);
            lds[row * 144 + q4] = pk4(v.x, v.y, v.z, v.w);
        }
        __syncthreads();
        #pragma unroll
        for (int i = 0; i < 18; ++i) {
            int idx = i * 256 + t, seg = idx / 192, off = idx - seg * 192;
            int row = off / 3, m3 = off - row * 3;
            int w0 = row * 144 + seg * 6 + m3 * 2;
            int2 v = { (int)lds[w0], (int)lds[w0 + 1] };
            *(int2*)(C6 + ((size_t)seg * R + r0) * 24 + (size_t)off * 8) = v;
        }
    } else if (b < 6 * per) {                      // ---- fp8: decode+scale to bf16
        int rb = b - 5 * per, r0 = rb << 6;
        #pragma unroll
        for (int i = 0; i < 16; ++i) {
            int idx = i * 256 + t, row = idx >> 6, q4 = idx & 63;
            int4 c = *(const int4*)(Po + (size_t)(r0 + row) * 256 + q4 * 4);
            int e = So[(size_t)(r0 + row) * 8 + (q4 >> 3)] - 127;
            lds[row * 128 + q4 * 2]     = dec8bf(c.x & 255, e) | (dec8bf(c.y & 255, e) << 16);
            lds[row * 128 + q4 * 2 + 1] = dec8bf(c.z & 255, e) | (dec8bf(c.w & 255, e) << 16);
        }
        __syncthreads();
        #pragma unroll
        for (int i = 0; i < 8; ++i) {
            int idx = i * 256 + t, seg = idx >> 6, row = idx & 63;
            uint4 v = *(uint4*)&lds[row * 128 + seg * 4];
            *(uint4*)((unsigned char*)C8 + ((size_t)seg * R + r0 + row) * 16) = v;
        }
    } else if (b < 7 * per) {                      // ---- fp4 scale quads
        int rb = b - 6 * per, r0 = rb << 6;
        #pragma unroll
        for (int i = 0; i < 6; ++i) {
            int idx = i * 256 + t, row = idx / 24, q4 = idx - row * 24;
            int4 v = *(const int4*)(Sn + (size_t)(r0 + row) * 96 + q4 * 4);
            lds[row * 24 + q4] = pk4(v.x, v.y, v.z, v.w);
        }
        __syncthreads();
        #pragma unroll
        for (int i = 0; i < 6; ++i) {
            int idx = i * 256 + t, seg = idx >> 6, row = idx & 63;
            *(unsigned*)(St + ((size_t)seg * R + r0 + row) * 4) = lds[row * 24 + seg];
        }
    } else {                                       // ---- fp6 scale pairs
        int rb = b - 7 * per, r0 = rb << 6;
        #pragma unroll
        for (int i = 0; i < 3; ++i) {
            int idx = i * 256 + t, row = idx / 12, b2 = idx - row * 12;
            int2 v = *(const int2*)(Ss + (size_t)(r0 + row) * 24 + b2 * 2);
            lds[row * 12 + b2] = (unsigned)((v.x & 255) | ((v.y & 255) << 8));
        }
        __syncthreads();
        #pragma unroll
        for (int i = 0; i < 3; ++i) {
            int idx = i * 256 + t, seg = idx >> 6, row = idx & 63;
            *(unsigned*)(St + ((size_t)(24 + seg) * R + r0 + row) * 4) = lds[row * 12 + seg];
        }
    }
}

__global__ __launch_bounds__(256) void pack_all(
    const int* __restrict__ AN, const int* __restrict__ AS, const int* __restrict__ AO,
    const int* __restrict__ SAn, const int* __restrict__ SAs, const int* __restrict__ SAo,
    unsigned char* __restrict__ A4, unsigned char* __restrict__ A6,
    unsigned short* __restrict__ A8, unsigned char* __restrict__ SaT, int M,
    const int* __restrict__ BN, const int* __restrict__ BS, const int* __restrict__ BO,
    const int* __restrict__ SBn, const int* __restrict__ SBs, const int* __restrict__ SBo,
    unsigned char* __restrict__ B4, unsigned char* __restrict__ B6,
    unsigned short* __restrict__ B8, unsigned char* __restrict__ SbT, int N)
{
    __shared__ unsigned lds[9216];                 // 36 KB, max section (fp6)
    int b = blockIdx.x, t = threadIdx.x;
    int nA = (M >> 6) * 8;
    if (b < nA) pack_side_lds(b, t, lds, AN, AS, AO, SAn, SAs, SAo, A4, A6, A8, SaT, M);
    else        pack_side_lds(b - nA, t, lds, BN, BS, BO, SBn, SBs, SBo, B4, B6, B8, SbT, N);
}

// ---- barrier-free direct-load MX GEMM v8: the r1-proven optimum (64x64 wave
// tile, (256,2), depth-4 fp4 / depth-2 fp6,fp8 register pipelines, ~100 arch
// VGPR, no spill) + two zero-cost schedule nudges:
//   (1) issue-early prefetch (T14): operands are copied out of the slot FIRST,
//       then the slot's prefetch loads are issued BEFORE the MFMA cluster --
//       ~140-200cy more latency lead per step at zero register cost.
//   (2) s_setprio(1) around each MFMA cluster (T5): waves here are barrier-free
//       and phase-drifted (the regime where setprio measured +4-7%).
// Ledger (all disproven): (256,3)/depth-6/wide-tile spill at the ~128-VGPR
// allocator clamp; per-step-barrier LDS staging locksteps; XCD swizzle null.
// Tail prefetch strays are bounded reads into the adjacent ws region
// (A4->B4->A6, A8->B8->SaT); fp6 tail (v=10,11) peeled.
__global__ __launch_bounds__(256, 2) void gemm_mx(
    const unsigned char* __restrict__ A4, const unsigned char* __restrict__ B4,
    const unsigned char* __restrict__ A6, const unsigned char* __restrict__ B6,
    const unsigned short* __restrict__ A8, const unsigned short* __restrict__ B8,
    const unsigned char* __restrict__ SaT, const unsigned char* __restrict__ SbT,
    const float* __restrict__ bias, float* __restrict__ C, int M, int N)
{
    int tid = threadIdx.x, w = tid >> 6, l = tid & 63;
    int bm = blockIdx.y, bn = blockIdx.x;
    int wm = (w >> 1) * 64, wn = (w & 1) * 64;
    int lr = l & 31, lh = l >> 5;

    floatx16 acc[2][2] = {};

    int rA[2] = { bm * 128 + wm + lr, bm * 128 + wm + 32 + lr };
    int cB[2] = { bn * 128 + wn + lr, bn * 128 + wn + 32 + lr };

    // ================= fp4 (fmt 4): 48 steps of K=64, depth-4 pipeline =================
    {
        unsigned strA = 32u * (unsigned)M, strB = 32u * (unsigned)N;
        unsigned fA0 = ((unsigned)lh * M + (unsigned)rA[0]) * 16u;
        unsigned fA1 = ((unsigned)lh * M + (unsigned)rA[1]) * 16u;
        unsigned fB0 = ((unsigned)lh * N + (unsigned)cB[0]) * 16u;
        unsigned fB1 = ((unsigned)lh * N + (unsigned)cB[1]) * 16u;

        int4 pa[4][2], pb[4][2];
        #pragma unroll
        for (int s = 0; s < 4; ++s) {
            pa[s][0] = *(const int4*)(A4 + fA0); pa[s][1] = *(const int4*)(A4 + fA1);
            pb[s][0] = *(const int4*)(B4 + fB0); pb[s][1] = *(const int4*)(B4 + fB1);
            fA0 += strA; fA1 += strA; fB0 += strB; fB1 += strB;
        }

        unsigned sstrA = 4u * (unsigned)M, sstrB = 4u * (unsigned)N;
        unsigned sA0 = (unsigned)rA[0] * 4u, sA1 = (unsigned)rA[1] * 4u;
        unsigned sB0 = (unsigned)cB[0] * 4u, sB1 = (unsigned)cB[1] * 4u;
        unsigned psa[2][2], psb[2][2];
        psa[0][0] = *(const unsigned*)(SaT + sA0);         psa[0][1] = *(const unsigned*)(SaT + sA1);
        psb[0][0] = *(const unsigned*)(SbT + sB0);         psb[0][1] = *(const unsigned*)(SbT + sB1);
        psa[1][0] = *(const unsigned*)(SaT + sA0 + sstrA); psa[1][1] = *(const unsigned*)(SaT + sA1 + sstrA);
        psb[1][0] = *(const unsigned*)(SbT + sB0 + sstrB); psb[1][1] = *(const unsigned*)(SbT + sB1 + sstrB);
        sA0 += 2 * sstrA; sA1 += 2 * sstrA; sB0 += 2 * sstrB; sB1 += 2 * sstrB;  // next: up=2

        #pragma unroll 4
        for (int u = 0; u < 48; ++u) {
            int sl = u & 3, wsl = (u >> 1) & 1;
            // (1) copy operands out of the slot FIRST...
            intx8 A0 = (intx8){ pa[sl][0].x, pa[sl][0].y, pa[sl][0].z, pa[sl][0].w, 0, 0, 0, 0 };
            intx8 A1 = (intx8){ pa[sl][1].x, pa[sl][1].y, pa[sl][1].z, pa[sl][1].w, 0, 0, 0, 0 };
            intx8 B0 = (intx8){ pb[sl][0].x, pb[sl][0].y, pb[sl][0].z, pb[sl][0].w, 0, 0, 0, 0 };
            intx8 B1 = (intx8){ pb[sl][1].x, pb[sl][1].y, pb[sl][1].z, pb[sl][1].w, 0, 0, 0, 0 };
            int sh = 8 * ((u & 1) * 2 + lh);
            int sa0 = (int)((psa[wsl][0] >> sh) & 255), sa1 = (int)((psa[wsl][1] >> sh) & 255);
            int sb0 = (int)((psb[wsl][0] >> sh) & 255), sb1 = (int)((psb[wsl][1] >> sh) & 255);
            // ...then issue step-u+4's prefetch BEFORE the MFMA cluster (issue-early)
            pa[sl][0] = *(const int4*)(A4 + fA0); pa[sl][1] = *(const int4*)(A4 + fA1);
            pb[sl][0] = *(const int4*)(B4 + fB0); pb[sl][1] = *(const int4*)(B4 + fB1);
            fA0 += strA; fA1 += strA; fB0 += strB; fB1 += strB;
            if (u & 1) {   // scale prefetch also issued before the MFMAs
                psa[wsl][0] = *(const unsigned*)(SaT + sA0); psa[wsl][1] = *(const unsigned*)(SaT + sA1);
                psb[wsl][0] = *(const unsigned*)(SbT + sB0); psb[wsl][1] = *(const unsigned*)(SbT + sB1);
                sA0 += sstrA; sA1 += sstrA; sB0 += sstrB; sB1 += sstrB;
            }
            __builtin_amdgcn_s_setprio(1);
            acc[0][0] = __builtin_amdgcn_mfma_scale_f32_32x32x64_f8f6f4(A0, B0, acc[0][0], 4, 4, 0, sa0, 0, sb0);
            acc[0][1] = __builtin_amdgcn_mfma_scale_f32_32x32x64_f8f6f4(A0, B1, acc[0][1], 4, 4, 0, sa0, 0, sb1);
            acc[1][0] = __builtin_amdgcn_mfma_scale_f32_32x32x64_f8f6f4(A1, B0, acc[1][0], 4, 4, 0, sa1, 0, sb0);
            acc[1][1] = __builtin_amdgcn_mfma_scale_f32_32x32x64_f8f6f4(A1, B1, acc[1][1], 4, 4, 0, sa1, 0, sb1);
            __builtin_amdgcn_s_setprio(0);
        }
    }

    // ================= fp6 (fmt 3): 12 steps of K=64, depth-2 pipeline =================
    {
        unsigned str6A = 48u * (unsigned)M, str6B = 48u * (unsigned)N;
        unsigned gA0 = ((unsigned)lh * M + (unsigned)rA[0]) * 24u;
        unsigned gA1 = ((unsigned)lh * M + (unsigned)rA[1]) * 24u;
        unsigned gB0 = ((unsigned)lh * N + (unsigned)cB[0]) * 24u;
        unsigned gB1 = ((unsigned)lh * N + (unsigned)cB[1]) * 24u;
        unsigned ss4A = 4u * (unsigned)M, ss4B = 4u * (unsigned)N;
        unsigned zA0 = (24u * (unsigned)M + (unsigned)rA[0]) * 4u;
        unsigned zA1 = (24u * (unsigned)M + (unsigned)rA[1]) * 4u;
        unsigned zB0 = (24u * (unsigned)N + (unsigned)cB[0]) * 4u;
        unsigned zB1 = (24u * (unsigned)N + (unsigned)cB[1]) * 4u;

        int2 qa[2][2][3], qb[2][2][3];
        unsigned p6a[2][2], p6b[2][2];
        #pragma unroll
        for (int s = 0; s < 2; ++s) {
            const unsigned char *a0 = A6 + gA0, *a1 = A6 + gA1, *b0 = B6 + gB0, *b1 = B6 + gB1;
            qa[s][0][0] = *(const int2*)(a0); qa[s][0][1] = *(const int2*)(a0 + 8); qa[s][0][2] = *(const int2*)(a0 + 16);
            qa[s][1][0] = *(const int2*)(a1); qa[s][1][1] = *(const int2*)(a1 + 8); qa[s][1][2] = *(const int2*)(a1 + 16);
            qb[s][0][0] = *(const int2*)(b0); qb[s][0][1] = *(const int2*)(b0 + 8); qb[s][0][2] = *(const int2*)(b0 + 16);
            qb[s][1][0] = *(const int2*)(b1); qb[s][1][1] = *(const int2*)(b1 + 8); qb[s][1][2] = *(const int2*)(b1 + 16);
            p6a[s][0] = *(const unsigned*)(SaT + zA0); p6a[s][1] = *(const unsigned*)(SaT + zA1);
            p6b[s][0] = *(const unsigned*)(SbT + zB0); p6b[s][1] = *(const unsigned*)(SbT + zB1);
            gA0 += str6A; gA1 += str6A; gB0 += str6B; gB1 += str6B;
            zA0 += ss4A; zA1 += ss4A; zB0 += ss4B; zB1 += ss4B;
        }
        int sh6 = 8 * lh;
        #pragma unroll 2
        for (int v = 0; v < 10; ++v) {
            int sl = v & 1;
            int sa0 = (int)((p6a[sl][0] >> sh6) & 255), sa1 = (int)((p6a[sl][1] >> sh6) & 255);
            int sb0 = (int)((p6b[sl][0] >> sh6) & 255), sb1 = (int)((p6b[sl][1] >> sh6) & 255);
            intx8 A0 = (intx8){ qa[sl][0][0].x, qa[sl][0][0].y, qa[sl][0][1].x, qa[sl][0][1].y, qa[sl][0][2].x, qa[sl][0][2].y, 0, 0 };
            intx8 A1 = (intx8){ qa[sl][1][0].x, qa[sl][1][0].y, qa[sl][1][1].x, qa[sl][1][1].y, qa[sl][1][2].x, qa[sl][1][2].y, 0, 0 };
            intx8 B0 = (intx8){ qb[sl][0][0].x, qb[sl][0][0].y, qb[sl][0][1].x, qb[sl][0][1].y, qb[sl][0][2].x, qb[sl][0][2].y, 0, 0 };
            intx8 B1 = (intx8){ qb[sl][1][0].x, qb[sl][1][0].y, qb[sl][1][1].x, qb[sl][1][1].y, qb[sl][1][2].x, qb[sl][1][2].y, 0, 0 };
            {   // issue-early: prefetch v+2 into the just-copied slot (v+2 <= 11)
                const unsigned char *a0 = A6 + gA0, *a1 = A6 + gA1, *b0 = B6 + gB0, *b1 = B6 + gB1;
                qa[sl][0][0] = *(const int2*)(a0); qa[sl][0][1] = *(const int2*)(a0 + 8); qa[sl][0][2] = *(const int2*)(a0 + 16);
                qa[sl][1][0] = *(const int2*)(a1); qa[sl][1][1] = *(const int2*)(a1 + 8); qa[sl][1][2] = *(const int2*)(a1 + 16);
                qb[sl][0][0] = *(const int2*)(b0); qb[sl][0][1] = *(const int2*)(b0 + 8); qb[sl][0][2] = *(const int2*)(b0 + 16);
                qb[sl][1][0] = *(const int2*)(b1); qb[sl][1][1] = *(const int2*)(b1 + 8); qb[sl][1][2] = *(const int2*)(b1 + 16);
                p6a[sl][0] = *(const unsigned*)(SaT + zA0); p6a[sl][1] = *(const unsigned*)(SaT + zA1);
                p6b[sl][0] = *(const unsigned*)(SbT + zB0); p6b[sl][1] = *(const unsigned*)(SbT + zB1);
                gA0 += str6A; gA1 += str6A; gB0 += str6B; gB1 += str6B;
                zA0 += ss4A; zA1 += ss4A; zB0 += ss4B; zB1 += ss4B;
            }
            __builtin_amdgcn_s_setprio(1);
            acc[0][0] = __builtin_amdgcn_mfma_scale_f32_32x32x64_f8f6f4(A0, B0, acc[0][0], 3, 3, 0, sa0, 0, sb0);
            acc[0][1] = __builtin_amdgcn_mfma_scale_f32_32x32x64_f8f6f4(A0, B1, acc[0][1], 3, 3, 0, sa0, 0, sb1);
            acc[1][0] = __builtin_amdgcn_mfma_scale_f32_32x32x64_f8f6f4(A1, B0, acc[1][0], 3, 3, 0, sa1, 0, sb0);
            acc[1][1] = __builtin_amdgcn_mfma_scale_f32_32x32x64_f8f6f4(A1, B1, acc[1][1], 3, 3, 0, sa1, 0, sb1);
            __builtin_amdgcn_s_setprio(0);
        }
        #pragma unroll
        for (int v = 10; v < 12; ++v) {   // peeled tail: consume-only (no stray scale reads)
            int sl = v & 1;
            int sa0 = (int)((p6a[sl][0] >> sh6) & 255), sa1 = (int)((p6a[sl][1] >> sh6) & 255);
            int sb0 = (int)((p6b[sl][0] >> sh6) & 255), sb1 = (int)((p6b[sl][1] >> sh6) & 255);
            intx8 A0 = (intx8){ qa[sl][0][0].x, qa[sl][0][0].y, qa[sl][0][1].x, qa[sl][0][1].y, qa[sl][0][2].x, qa[sl][0][2].y, 0, 0 };
            intx8 A1 = (intx8){ qa[sl][1][0].x, qa[sl][1][0].y, qa[sl][1][1].x, qa[sl][1][1].y, qa[sl][1][2].x, qa[sl][1][2].y, 0, 0 };
            intx8 B0 = (intx8){ qb[sl][0][0].x, qb[sl][0][0].y, qb[sl][0][1].x, qb[sl][0][1].y, qb[sl][0][2].x, qb[sl][0][2].y, 0, 0 };
            intx8 B1 = (intx8){ qb[sl][1][0].x, qb[sl][1][0].y, qb[sl][1][1].x, qb[sl][1][1].y, qb[sl][1][2].x, qb[sl][1][2].y, 0, 0 };
            acc[0][0] = __builtin_amdgcn_mfma_scale_f32_32x32x64_f8f6f4(A0, B0, acc[0][0], 3, 3, 0, sa0, 0, sb0);
            acc[0][1] = __builtin_amdgcn_mfma_scale_f32_32x32x64_f8f6f4(A0, B1, acc[0][1], 3, 3, 0, sa0, 0, sb1);
            acc[1][0] = __builtin_amdgcn_mfma_scale_f32_32x32x64_f8f6f4(A1, B0, acc[1][0], 3, 3, 0, sa1, 0, sb0);
            acc[1][1] = __builtin_amdgcn_mfma_scale_f32_32x32x64_f8f6f4(A1, B1, acc[1][1], 3, 3, 0, sa1, 0, sb1);
        }
    }

    // ================= fp8 as bf16: 16 steps of K=16, depth-2 pipeline =================
    {
        unsigned str8A = 32u * (unsigned)M, str8B = 32u * (unsigned)N;
        const unsigned char* A8b = (const unsigned char*)A8;
        const unsigned char* B8b = (const unsigned char*)B8;
        unsigned hA0 = ((unsigned)lh * M + (unsigned)rA[0]) * 16u;
        unsigned hA1 = ((unsigned)lh * M + (unsigned)rA[1]) * 16u;
        unsigned hB0 = ((unsigned)lh * N + (unsigned)cB[0]) * 16u;
        unsigned hB1 = ((unsigned)lh * N + (unsigned)cB[1]) * 16u;
        short8 ra[2][2], rb[2][2];
        #pragma unroll
        for (int s = 0; s < 2; ++s) {
            ra[s][0] = *(const short8*)(A8b + hA0); ra[s][1] = *(const short8*)(A8b + hA1);
            rb[s][0] = *(const short8*)(B8b + hB0); rb[s][1] = *(const short8*)(B8b + hB1);
            hA0 += str8A; hA1 += str8A; hB0 += str8B; hB1 += str8B;
        }
        #pragma unroll 2
        for (int q = 0; q < 16; ++q) {
            int sl = q & 1;
            short8 a0 = ra[sl][0], a1 = ra[sl][1], b0 = rb[sl][0], b1 = rb[sl][1];
            // issue-early: prefetch q+2 before the MFMA cluster (tail strays stay
            // inside A8->B8 / B8->SaT regions)
            ra[sl][0] = *(const short8*)(A8b + hA0); ra[sl][1] = *(const short8*)(A8b + hA1);
            rb[sl][0] = *(const short8*)(B8b + hB0); rb[sl][1] = *(const short8*)(B8b + hB1);
            hA0 += str8A; hA1 += str8A; hB0 += str8B; hB1 += str8B;
            __builtin_amdgcn_s_setprio(1);
            acc[0][0] = __builtin_amdgcn_mfma_f32_32x32x16_bf16(a0, b0, acc[0][0], 0, 0, 0);
            acc[0][1] = __builtin_amdgcn_mfma_f32_32x32x16_bf16(a0, b1, acc[0][1], 0, 0, 0);
            acc[1][0] = __builtin_amdgcn_mfma_f32_32x32x16_bf16(a1, b0, acc[1][0], 0, 0, 0);
            acc[1][1] = __builtin_amdgcn_mfma_f32_32x32x16_bf16(a1, b1, acc[1][1], 0, 0, 0);
            __builtin_amdgcn_s_setprio(0);
        }
    }

    // epilogue: 32x32 C/D layout col=lane&31, row=(r&3)+8*(r>>2)+4*lh (m74/m101-verified)
    #pragma unroll
    for (int i = 0; i < 2; i++)
        #pragma unroll
        for (int j = 0; j < 2; j++) {
            int col = bn * 128 + wn + j * 32 + lr;
            float bv = bias[col];
            #pragma unroll
            for (int r = 0; r < 16; r++) {
                int row = bm * 128 + wm + i * 32 + (r & 3) + 8 * (r >> 2) + 4 * lh;
                C[(size_t)row * N + col] = acc[i][j][r] + bv;
            }
        }
}

extern "C" void kernel_launch(void* const* d_in, const int* in_sizes, int n_in,
                              void* d_out, int out_size, void* d_ws, size_t ws_size,
                              hipStream_t stream) {
    const int* AN   = (const int*)d_in[0];
    const int* ASs  = (const int*)d_in[1];
    const int* AO   = (const int*)d_in[2];
    const int* SFAN = (const int*)d_in[3];
    const int* SFAS = (const int*)d_in[4];
    const int* SFAO = (const int*)d_in[5];
    const int* BN   = (const int*)d_in[6];
    const int* BS   = (const int*)d_in[7];
    const int* BO   = (const int*)d_in[8];
    const int* SFBN = (const int*)d_in[9];
    const int* SFBS = (const int*)d_in[10];
    const int* SFBO = (const int*)d_in[11];
    const float* bias = (const float*)d_in[12];

    int M = in_sizes[0] / 1536;
    int N = in_sizes[6] / 1536;

    unsigned char* ws = (unsigned char*)d_ws;
    size_t o = 0;
    unsigned char*  A4c = ws + o;                    o += (size_t)M * 1536;
    unsigned char*  B4c = ws + o;                    o += (size_t)N * 1536;
    unsigned char*  A6c = ws + o;                    o += (size_t)M * 576;
    unsigned char*  B6c = ws + o;                    o += (size_t)N * 576;
    unsigned short* A8d = (unsigned short*)(ws + o); o += (size_t)M * 512;
    unsigned short* B8d = (unsigned short*)(ws + o); o += (size_t)N * 512;
    unsigned char*  SaT = ws + o;                    o += (size_t)36 * M * 4;
    unsigned char*  SbT = ws + o;                    o += (size_t)36 * N * 4;

    int nblk = (M >> 6) * 8 + (N >> 6) * 8;
    pack_all<<<nblk, 256, 0, stream>>>(
        AN, ASs, AO, SFAN, SFAS, SFAO, A4c, A6c, A8d, SaT, M,
        BN, BS, BO, SFBN, SFBS, SFBO, B4c, B6c, B8d, SbT, N);

    dim3 grid(N / 128, M / 128);
    gemm_mx<<<grid, 256, 0, stream>>>(A4c, B4c, A6c, B6c, A8d, B8d,
                                      SaT, SbT, bias, (float*)d_out, M, N);
}